// Round 10
// baseline (33.409 us; speedup 1.0000x reference)
//
#include <hip/hip_runtime.h>
#include <hip/hip_bf16.h>

// FilterbankLinear: out[b, j*8+o] = sum_{c,t} x[b,c,s_j+t] * w[j*8+o, c*32+t]
// s_j = j (j<4063), s_4063 = 4064.
// TRAFFIC-MINIMIZED: block = 16 windows (254 blocks, 1/CU), 512 thr / 8 waves,
// wave handles 2 windows x 2 M-tiles (R3-proven consume path). x staged as
// 13 chunks/row (52 floats; 12 consumed) -> x-stage overfetch 93MB -> 35.5MB.
// 13-chunk row stride: odd (conflict-free b128) AND LDS linear in chunk index
// (global_load_lds wave-uniform dest + lane*16). Triple-buffer, depth-2 stage,
// counted vmcnt + raw s_barrier. w: float4 register prefetch depth-1.

#define NF 4096
#define NC 21
#define WIN 32
#define OC 8
#define NWIN 4064
#define NKTOT (OC * NWIN)
#define DD (NC * WIN)       // 672
#define JB 16
#define NBLK (NWIN / JB)    // 254
#define CHK 13              // staged chunks per row (16B each); chunk 12 never consumed
#define XROWB (CHK * 16)    // 208
#define XBUFB (32 * XROWB)  // 6656 = 416 chunks

typedef short short8 __attribute__((ext_vector_type(8)));
typedef float f32x4 __attribute__((ext_vector_type(4)));

static __device__ __forceinline__ short f2bf(float f) {
  __bf16 h = (__bf16)f;
  return __builtin_bit_cast(short, h);
}
static __device__ __forceinline__ short8 pk8(float a, float b, float c, float d,
                                             float e, float f, float g, float h) {
  short8 v;
  v[0]=f2bf(a); v[1]=f2bf(b); v[2]=f2bf(c); v[3]=f2bf(d);
  v[4]=f2bf(e); v[5]=f2bf(f); v[6]=f2bf(g); v[7]=f2bf(h);
  return v;
}
// select 8 consecutive floats out of 12 by wave-uniform u (static indices only)
static __device__ __forceinline__ short8 sel8(f32x4 a, f32x4 b, f32x4 c, int u) {
  switch (u & 3) {
    case 0:  return pk8(a[0],a[1],a[2],a[3],b[0],b[1],b[2],b[3]);
    case 1:  return pk8(a[1],a[2],a[3],b[0],b[1],b[2],b[3],c[0]);
    case 2:  return pk8(a[2],a[3],b[0],b[1],b[2],b[3],c[0],c[1]);
    default: return pk8(a[3],b[0],b[1],b[2],b[3],c[0],c[1],c[2]);
  }
}

#define VMW(N) asm volatile("s_waitcnt vmcnt(" #N ")" ::: "memory")
#define BAR() { __builtin_amdgcn_s_barrier(); __builtin_amdgcn_sched_barrier(0); }

#define GLL(GP, LOFF) \
  __builtin_amdgcn_global_load_lds( \
    (const __attribute__((address_space(1))) unsigned int*)(GP), \
    (__attribute__((address_space(3))) unsigned int*)(xlds + (LOFF)), 16, 0, 0)

__global__ __launch_bounds__(512) void fb_j16(const float* __restrict__ x,
                                              const float* __restrict__ w,
                                              float* __restrict__ out) {
  __shared__ __align__(16) char xlds[3 * XBUFB + 1024];   // + guard pad
  const int tid  = threadIdx.x;
  const int lane = tid & 63;
  const int wv   = tid >> 6;          // 0..7

  // bijective XCD swizzle (nwg=254: xcd<6 -> 32 blocks each, xcd 6,7 -> 31)
  const int orig = blockIdx.x;
  const int xcd = orig & 7, idx = orig >> 3;
  const int blk = (xcd < 6 ? xcd * 32 : 192 + (xcd - 6) * 31) + idx;
  const int j0 = blk * JB;            // 16-aligned -> x+j0 is 16B aligned

  const int n  = lane & 15;
  const int o  = n & 7;
  const int hi = lane >> 4;           // k-quarter 0..3
  const int Ckb = hi * 32;            // byte offset of k-slice (2 chunks)
  const int boff0 = n * XROWB, boff1 = (16 + n) * XROWB;

  // this wave's two windows
  const int jg0 = j0 + 2 * wv, jg1 = jg0 + 1;
  const int s1  = (jg1 == NWIN - 1) ? (NF - WIN) : jg1;
  const int rj0 = 2 * wv, rj1 = s1 - j0;        // 0..15, plus 16 on last blk
  const int u0 = rj0 & 3, u1 = rj1 & 3;
  const int o00 = boff0 + (rj0 >> 2) * 16 + Ckb;
  const int o01 = boff1 + (rj0 >> 2) * 16 + Ckb;
  const int o10 = boff0 + (rj1 >> 2) * 16 + Ckb;
  const int o11 = boff1 + (rj1 >> 2) * 16 + Ckb;

  // staging: chunk q = tid (q<416); row = q/13, chunk-in-row = q%13.
  // chunk 12 is staged-but-never-consumed: clamp its addr (avoids OOB at x end)
  int q = (tid <= 415) ? tid : 415;
  const int row = q / CHK, cs = q - row * CHK;
  const int csc = (cs <= 11) ? cs : 11;
  const float* xsp = x + (size_t)row * (NC * NF) + j0 + csc * 4;
  const int sdo = wv * 1024;          // per-wave LDS chunk base (wave-uniform)

#define STG(CH, NB) { \
    if (wv < 6)       { GLL(xsp + (CH) * NF, (NB) * XBUFB + sdo); } \
    else if (wv == 6) { if (lane < 32) { GLL(xsp + (CH) * NF, (NB) * XBUFB + sdo); } } }

  const float* wp0 = w + ((size_t)jg0 * OC + o) * DD + hi * 8;
  const float* wp1 = w + ((size_t)jg1 * OC + o) * DD + hi * 8;

  f32x4 acc00 = {0,0,0,0}, acc01 = {0,0,0,0}, acc10 = {0,0,0,0}, acc11 = {0,0,0,0};

  // ---- prologue: stage ch0 -> B0, ch1 -> B1; w(ch0) -> regs ----
  STG(0, 0);
  STG(1, 1);
  float4 w0a = *(const float4*)(wp0), w0b = *(const float4*)(wp0 + 4);
  float4 w1a = *(const float4*)(wp1), w1b = *(const float4*)(wp1 + 4);

  #pragma unroll
  for (int c = 0; c < NC; ++c) {
    // stage(c) complete; stage(c+1) [<=1] + w(c) [4] stay in flight
    if (c < NC - 1) { VMW(5); } else { VMW(0); }
    BAR();

    if (c + 2 < NC) { STG(c + 2, (c + 2) % 3); }
    float4 w0an = {0,0,0,0}, w0bn = {0,0,0,0}, w1an = {0,0,0,0}, w1bn = {0,0,0,0};
    if (c + 1 < NC) {
      w0an = *(const float4*)(wp0 + (c + 1) * WIN);
      w0bn = *(const float4*)(wp0 + (c + 1) * WIN + 4);
      w1an = *(const float4*)(wp1 + (c + 1) * WIN);
      w1bn = *(const float4*)(wp1 + (c + 1) * WIN + 4);
    }

    const char* xb = xlds + (c % 3) * XBUFB;
    {   // window 0
      short8 fbw = pk8(w0a.x,w0a.y,w0a.z,w0a.w,w0b.x,w0b.y,w0b.z,w0b.w);
      f32x4 ra = *(const f32x4*)(xb + o00);
      f32x4 rb = *(const f32x4*)(xb + o00 + 16);
      f32x4 rc = *(const f32x4*)(xb + o00 + 32);
      acc00 = __builtin_amdgcn_mfma_f32_16x16x32_bf16(sel8(ra,rb,rc,u0), fbw, acc00, 0,0,0);
      ra = *(const f32x4*)(xb + o01);
      rb = *(const f32x4*)(xb + o01 + 16);
      rc = *(const f32x4*)(xb + o01 + 32);
      acc01 = __builtin_amdgcn_mfma_f32_16x16x32_bf16(sel8(ra,rb,rc,u0), fbw, acc01, 0,0,0);
    }
    {   // window 1
      short8 fbw = pk8(w1a.x,w1a.y,w1a.z,w1a.w,w1b.x,w1b.y,w1b.z,w1b.w);
      f32x4 ra = *(const f32x4*)(xb + o10);
      f32x4 rb = *(const f32x4*)(xb + o10 + 16);
      f32x4 rc = *(const f32x4*)(xb + o10 + 32);
      acc10 = __builtin_amdgcn_mfma_f32_16x16x32_bf16(sel8(ra,rb,rc,u1), fbw, acc10, 0,0,0);
      ra = *(const f32x4*)(xb + o11);
      rb = *(const f32x4*)(xb + o11 + 16);
      rc = *(const f32x4*)(xb + o11 + 32);
      acc11 = __builtin_amdgcn_mfma_f32_16x16x32_bf16(sel8(ra,rb,rc,u1), fbw, acc11, 0,0,0);
    }
    w0a = w0an; w0b = w0bn; w1a = w1an; w1b = w1bn;
  }

#undef STG

  if (n < 8) {
    const int m0 = hi * 4;
    #pragma unroll
    for (int e = 0; e < 4; ++e) {
      out[(size_t)(m0 + e)      * NKTOT + (size_t)jg0 * OC + n] = acc00[e];
      out[(size_t)(m0 + e + 16) * NKTOT + (size_t)jg0 * OC + n] = acc01[e];
      out[(size_t)(m0 + e)      * NKTOT + (size_t)jg1 * OC + n] = acc10[e];
      out[(size_t)(m0 + e + 16) * NKTOT + (size_t)jg1 * OC + n] = acc11[e];
    }
  }
}

extern "C" void kernel_launch(void* const* d_in, const int* in_sizes, int n_in,
                              void* d_out, int out_size, void* d_ws, size_t ws_size,
                              hipStream_t stream) {
  const float* x = (const float*)d_in[0];
  const float* w = (const float*)d_in[1];
  float* out = (float*)d_out;
  dim3 grid(NBLK), block(512);
  hipLaunchKernelGGL(fb_j16, grid, block, 0, stream, x, w, out);
}